// Round 6
// baseline (289.237 us; speedup 1.0000x reference)
//
#include <hip/hip_runtime.h>

#define HIDDEN    128
#define TPB       1024
#define PPT       20             // paths/thread: 60 ids + 20 acc ~= 100 VGPR (128 budget)
#define CN        38400          // nodes per plane-chunk (single l) staged in LDS
#define CN2       76800          // bytes per full plane-chunk (CN * 2) = 75 KiB
#define BUF1      76816          // 16-aligned base of buffer 1 (gap holds zero slot 0)
#define ZERO_GAP  76800          // zero slot offset WITHIN a buffer (= CN2)
#define LDS_BYTES 153620         // buf0 + zero0 + pad + buf1 + zero1
#define UNITS     (CN2 / 1024)   // 75 x 1KB wave-units per full chunk

typedef unsigned short u16;
typedef unsigned int   u32;

static __device__ __forceinline__ u16 f32_to_f16_bits(float x) {
    union { _Float16 h; u16 u; } cv;
    cv.h = (_Float16)x;
    return cv.u;
}

// Async global->LDS DMA, 16 B per lane: lane i's 16 B from its own global
// address land at (wave-uniform lds base) + i*16.
static __device__ __forceinline__ void gload_lds16(const void* gp, void* lp) {
    __builtin_amdgcn_global_load_lds(
        (const __attribute__((address_space(1))) unsigned int*)gp,
        (__attribute__((address_space(3))) unsigned int*)lp,
        16, 0, 0);
}

// Kernel 1: f16 projection table in PLANE-MAJOR layout:
//   proj_h[l * n_nodes + node]  (3 planes of n_nodes f16 each, 600000 B total).
// One wave per node. Fill overread (last chunk rounds to 1 KB units) stays
// inside the workspace: max read end = 2*200000 + 153600 + 47104 = 600704 B.
__global__ __launch_bounds__(256) void proj_kernel(
    const float* __restrict__ feat,   // (n_nodes, 128)
    const float* __restrict__ W,      // (3, 1, 128)
    u16* __restrict__ proj_h,         // 3 * n_nodes f16, plane-major
    int n_nodes)
{
    int gtid = blockIdx.x * blockDim.x + threadIdx.x;
    int node = gtid >> 6;
    int lane = threadIdx.x & 63;
    if (node >= n_nodes) return;

    const float2* f2 = (const float2*)(feat + (size_t)node * HIDDEN);
    const float2* w2 = (const float2*)W;

    float2 f   = f2[lane];
    float2 w0  = w2[lane];           // W[0]
    float2 w1  = w2[64 + lane];      // W[1]
    float2 wv2 = w2[128 + lane];     // W[2]

    float s0 = f.x * w0.x  + f.y * w0.y;
    float s1 = f.x * w1.x  + f.y * w1.y;
    float s2 = f.x * wv2.x + f.y * wv2.y;

    #pragma unroll
    for (int off = 32; off > 0; off >>= 1) {
        s0 += __shfl_xor(s0, off, 64);
        s1 += __shfl_xor(s1, off, 64);
        s2 += __shfl_xor(s2, off, 64);
    }

    if (lane == 0) {
        u16* base = proj_h + node;
        base[0]                   = f32_to_f16_bits(s0);
        base[n_nodes]             = f32_to_f16_bits(s1);
        base[2 * (size_t)n_nodes] = f32_to_f16_bits(s2);
    }
}

// Kernel 2 (fast path, nh==3): plane-split, double-buffered, FULLY UNROLLED
// 9-pass loop, PPT=20 at the 128-VGPR budget.
//
// R5 post-mortem: 814 blocks = 3.18 rounds -> makespan quantizes to 4 rounds
// of T_block ~= 17.5 us, where ~5 us/block is FIXED fill cost (600 KB whatever
// PPT is). score ~= R*(5 + k*PPT) with R*PPT*1024 ~= 10M paths: minimized at
// R=2 (PPT=20, 489 blocks). PPT=20 needs ~100 VGPR, which is free here: LDS
// (153.6 KB) caps the CU at 16 waves = 4 waves/SIMD, and 4 waves/SIMD allows
// 128 VGPR. amdgpu_waves_per_eu(4,4) pins that so the allocator doesn't
// squeeze to a 64-reg/8-wave target (the R1/R3 spill cause).
//
// Gather clamp: off = min(loc2, CN2); each buffer has a zero u32 at buf+CN2,
// so misses are a same-address LDS broadcast (conflict-free) and the select
// is one v_min_u32. Fully-unrolled passes make cb2/bb compile-time.
__global__ __launch_bounds__(TPB)
__attribute__((amdgpu_waves_per_eu(4, 4)))
void score_kernel(
    const int* __restrict__ paths,    // (n_paths, 3) int32
    const u16* __restrict__ proj_h,   // plane-major f16 table
    float* __restrict__ out,          // (n_paths,)
    int n_paths, int n_nodes)
{
    extern __shared__ u16 lds[];
    char* ldsb = (char*)lds;

    int base = blockIdx.x * (TPB * PPT) + threadIdx.x;
    int wid  = threadIdx.x >> 6;
    int lane = threadIdx.x & 63;

    const unsigned char* tab = (const unsigned char*)proj_h;
    int plane_b = 2 * n_nodes;                   // bytes per plane (200000)

    // Prologue: start chunk-0 DMA into buf0 first; it overlaps the path loads.
    for (int j = wid; j < UNITS; j += TPB / 64)
        gload_lds16(tab + (size_t)j * 1024 + lane * 16, ldsb + j * 1024);

    if (threadIdx.x == 0) {                      // both zero slots, pre-barrier
        *(u32*)(ldsb + ZERO_GAP)        = 0;     // byte 76800 (gap before BUF1)
        *(u32*)(ldsb + BUF1 + ZERO_GAP) = 0;     // byte 153616
    }

    // ids pre-doubled (byte offsets, sign preserved: -1 -> -2). Static indices.
    int id2[3 * PPT];
    #pragma unroll
    for (int k = 0; k < PPT; ++k) {
        int idx = base + k * TPB;
        int ii  = idx < n_paths ? idx : (n_paths - 1);   // clamp: uniform flow
        const int* pp = paths + (size_t)ii * 3;
        id2[3*k+0] = __builtin_nontemporal_load(pp + 0) << 1;
        id2[3*k+1] = __builtin_nontemporal_load(pp + 1) << 1;
        id2[3*k+2] = __builtin_nontemporal_load(pp + 2) << 1;
    }

    float acc[PPT];
    #pragma unroll
    for (int k = 0; k < PPT; ++k) acc[k] = 0.0f;

    __syncthreads();                             // chunk-0 fill complete

    #pragma unroll
    for (int c = 0; c < 9; ++c) {
        const int h   = c / 3;
        const int l   = c - 3 * h;               // compile-time: id2 idx static
        const int cb2 = h * CN2;
        const int bb  = (c & 1) ? BUF1 : 0;

        // Issue next chunk's async fill into the other buffer; it has the
        // whole gather phase to land before the barrier's vmcnt drain.
        if (c + 1 < 9) {
            const int hn   = (c + 1) / 3;
            const int ln   = (c + 1) - 3 * hn;
            const int nb   = ((c + 1) & 1) ? BUF1 : 0;
            const int ncb2 = hn * CN2;
            int rem   = plane_b - ncb2;
            int units = rem >= CN2 ? UNITS : ((rem + 1023) >> 10);
            const unsigned char* src = tab + (size_t)ln * plane_b + ncb2;
            for (int j = wid; j < units; j += TPB / 64)
                gload_lds16(src + (size_t)j * 1024 + lane * 16,
                            ldsb + nb + j * 1024);
        }

        // Gather: sub, min, ds_read_u16, cvt, add per attempt.
        #pragma unroll
        for (int k = 0; k < PPT; ++k) {
            u32 loc2 = (u32)(id2[3*k + l] - cb2);   // below-range/-1 => wraps huge
            u32 off  = loc2 < (u32)CN2 ? loc2 : (u32)CN2;  // v_min_u32 -> zero slot
            union { u16 u; _Float16 hh; } cv;
            cv.u = *(const u16*)(ldsb + bb + off);
            acc[k] += (float)cv.hh;
        }

        if (c + 1 < 9) __syncthreads();          // fill done + reads done
    }

    #pragma unroll
    for (int k = 0; k < PPT; ++k) {
        int idx = base + k * TPB;
        if (idx < n_paths) {
            int cnt = (int)(id2[3*k] >= 0) + (int)(id2[3*k+1] >= 0)
                    + (int)(id2[3*k+2] >= 0);
            float inv = (cnt == 3) ? (1.0f/3.0f) : (cnt == 2 ? 0.5f : 1.0f);
            __builtin_nontemporal_store(acc[k] * inv, out + idx);
        }
    }
}

// Generic fallback (nh != 3) — insurance only; never taken at n_nodes=100000.
// Separate function so its runtime-h loop can't perturb the hot kernel's
// register allocation.
__global__ __launch_bounds__(TPB)
__attribute__((amdgpu_waves_per_eu(4, 4)))
void score_generic(
    const int* __restrict__ paths, const u16* __restrict__ proj_h,
    float* __restrict__ out, int n_paths, int n_nodes, int nh)
{
    extern __shared__ u16 lds[];
    char* ldsb = (char*)lds;

    int base = blockIdx.x * (TPB * PPT) + threadIdx.x;
    int wid  = threadIdx.x >> 6;
    int lane = threadIdx.x & 63;

    const unsigned char* tab = (const unsigned char*)proj_h;
    int plane_b = 2 * n_nodes;
    int NC      = 3 * nh;

    {
        int units0 = plane_b >= CN2 ? UNITS : ((plane_b + 1023) >> 10);
        for (int j = wid; j < units0; j += TPB / 64)
            gload_lds16(tab + (size_t)j * 1024 + lane * 16, ldsb + j * 1024);
    }
    if (threadIdx.x == 0) {
        *(u32*)(ldsb + ZERO_GAP)        = 0;
        *(u32*)(ldsb + BUF1 + ZERO_GAP) = 0;
    }

    int id2[3 * PPT];
    #pragma unroll
    for (int k = 0; k < PPT; ++k) {
        int idx = base + k * TPB;
        int ii  = idx < n_paths ? idx : (n_paths - 1);
        const int* pp = paths + (size_t)ii * 3;
        id2[3*k+0] = __builtin_nontemporal_load(pp + 0) << 1;
        id2[3*k+1] = __builtin_nontemporal_load(pp + 1) << 1;
        id2[3*k+2] = __builtin_nontemporal_load(pp + 2) << 1;
    }

    float acc[PPT];
    #pragma unroll
    for (int k = 0; k < PPT; ++k) acc[k] = 0.0f;

    __syncthreads();

    for (int h = 0; h < nh; ++h) {
        #pragma unroll
        for (int l = 0; l < 3; ++l) {            // l compile-time: id2 static
            int c = h * 3 + l;
            if (c + 1 < NC) {
                int       hn = (l == 2) ? (h + 1) : h;
                const int ln = (l == 2) ? 0 : (l + 1);
                int       nb = ((c + 1) & 1) ? BUF1 : 0;
                const unsigned char* src = tab + (size_t)ln * plane_b
                                               + (size_t)hn * CN2;
                int rem   = plane_b - hn * CN2;
                int units = rem >= CN2 ? UNITS : ((rem + 1023) >> 10);
                for (int j = wid; j < units; j += TPB / 64)
                    gload_lds16(src + (size_t)j * 1024 + lane * 16,
                                ldsb + nb + j * 1024);
            }
            int cb2 = h * CN2;
            int bb  = (c & 1) ? BUF1 : 0;
            #pragma unroll
            for (int k = 0; k < PPT; ++k) {
                u32 loc2 = (u32)(id2[3*k + l] - cb2);
                u32 off  = loc2 < (u32)CN2 ? loc2 : (u32)CN2;
                union { u16 u; _Float16 hh; } cv;
                cv.u = *(const u16*)(ldsb + bb + off);
                acc[k] += (float)cv.hh;
            }
            if (c + 1 < NC) __syncthreads();
        }
    }

    #pragma unroll
    for (int k = 0; k < PPT; ++k) {
        int idx = base + k * TPB;
        if (idx < n_paths) {
            int cnt = (int)(id2[3*k] >= 0) + (int)(id2[3*k+1] >= 0)
                    + (int)(id2[3*k+2] >= 0);
            float inv = (cnt == 3) ? (1.0f/3.0f) : (cnt == 2 ? 0.5f : 1.0f);
            __builtin_nontemporal_store(acc[k] * inv, out + idx);
        }
    }
}

extern "C" void kernel_launch(void* const* d_in, const int* in_sizes, int n_in,
                              void* d_out, int out_size, void* d_ws, size_t ws_size,
                              hipStream_t stream) {
    const int*   paths = (const int*)d_in[0];     // (N_PATHS, 3) int32
    const float* feat  = (const float*)d_in[1];   // (N_NODES, 128) f32
    const float* W     = (const float*)d_in[2];   // (3, 1, 128) f32
    float*       out   = (float*)d_out;           // (N_PATHS,) f32

    int n_nodes = in_sizes[1] / HIDDEN;           // 100000
    int n_paths = in_sizes[0] / 3;                // 10000000
    u16* proj_h = (u16*)d_ws;                     // 3 planes * n_nodes f16

    int nh = (n_nodes + CN - 1) / CN;             // 3 at n_nodes=100000
    size_t lds_bytes = LDS_BYTES;                 // 153620

    (void)hipGetLastError();   // clear any sticky error pre-capture

    // Kernel 1: 1 wave per node, 4 waves per 256-thread block.
    {
        int blocks = (n_nodes + 3) / 4;
        proj_kernel<<<blocks, 256, 0, stream>>>(feat, W, proj_h, n_nodes);
    }

    // Kernel 2: 489 blocks (2 rounds of <=256 at 1 block/CU).
    {
        int blocks = (n_paths + TPB * PPT - 1) / (TPB * PPT);  // 489
        if (nh == 3) {
            (void)hipFuncSetAttribute((const void*)score_kernel,
                    hipFuncAttributeMaxDynamicSharedMemorySize, (int)lds_bytes);
            score_kernel<<<blocks, TPB, lds_bytes, stream>>>(
                paths, proj_h, out, n_paths, n_nodes);
        } else {
            (void)hipFuncSetAttribute((const void*)score_generic,
                    hipFuncAttributeMaxDynamicSharedMemorySize, (int)lds_bytes);
            score_generic<<<blocks, TPB, lds_bytes, stream>>>(
                paths, proj_h, out, n_paths, n_nodes, nh);
        }
    }
}